// Round 2
// baseline (695.733 us; speedup 1.0000x reference)
//
#include <hip/hip_runtime.h>

#define E_CONST 3
#define T_CONST 100
#define S_CONST 8192
#define NB 1024
#define INV_SIGMA 10.0f
#define ALPHA_C 0.05f

// ---------------------------------------------------------------------------
// Kernel 1: per-(i,s) cumsum over T, write transposed cumT[i][tau][s],
// plus per-(i,k) packed metadata (t, lab).
// ---------------------------------------------------------------------------
__global__ __launch_bounds__(64) void prep_kernel(
    const float* __restrict__ event_out,  // (E, S, T)
    const int* __restrict__ et,           // (S, E)
    const int* __restrict__ labs,         // (S, E)
    float* __restrict__ cumT,             // (E, T, S)
    int* __restrict__ tlA,                // (E, S) packed t | lab<<16
    int S)
{
    __shared__ float tile[64][T_CONST + 1];
    const int tilesPerEvent = S / 64;
    const int i  = blockIdx.x / tilesPerEvent;
    const int s0 = (blockIdx.x % tilesPerEvent) * 64;
    const int tid = threadIdx.x;

    const float* src = event_out + ((size_t)i * S + s0) * T_CONST;
    for (int idx = tid; idx < 64 * T_CONST; idx += 64) {
        int row = idx / T_CONST;
        int col = idx - row * T_CONST;
        tile[row][col] = src[idx];
    }
    __syncthreads();

    float run = 0.f;
    for (int tau = 0; tau < T_CONST; ++tau) {
        run += tile[tid][tau];
        tile[tid][tau] = run;
    }
    __syncthreads();

    float* dst = cumT + (size_t)i * T_CONST * S + s0;
    for (int idx = tid; idx < 64 * T_CONST; idx += 64) {
        int tau = idx >> 6;
        int sl  = idx & 63;
        dst[(size_t)tau * S + sl] = tile[sl][tau];
    }

    const int s   = s0 + tid;
    const int t   = et[s * E_CONST + i];
    const int lab = labs[s * E_CONST + i];
    tlA[i * S + s] = (t & 0xffff) | (lab << 16);
}

// ---------------------------------------------------------------------------
// Kernel 2: one block per (i,tau). Counting-sort the column cumT[i][tau][:]
// into NB min/max-normalized buckets; histogram prefix/suffix sums give the
// bulk of each query's threshold sum exactly (bucket map is monotone, so
// cross-bucket comparisons are exact); own-bucket members resolved by scan.
// ---------------------------------------------------------------------------
__global__ __launch_bounds__(256) void bucket_kernel(
    const float* __restrict__ cumT,
    const int* __restrict__ tlA,
    float* __restrict__ partials,
    int S)
{
    __shared__ float sortedV[S_CONST];
    __shared__ unsigned char sortedM[S_CONST];   // t(7b) | lab<<7
    __shared__ float wF[NB];
    __shared__ float wB[NB];
    __shared__ int   cnt[NB];                    // counts, then scatter cursor
    __shared__ int   offs[NB + 1];
    __shared__ float wshf[4];
    __shared__ int   wshi[4];
    __shared__ float mnSh[4], mxSh[4];

    const int tid  = threadIdx.x;
    const int lane = tid & 63;
    const int wid  = tid >> 6;
    const int bx   = blockIdx.x;
    const int i    = bx / T_CONST;
    const int tau  = bx - i * T_CONST;

    const float* __restrict__ col = cumT + ((size_t)i * T_CONST + tau) * S;
    const int*   __restrict__ tlp = tlA + (size_t)i * S;

    // zero histograms
    for (int b = tid; b < NB; b += 256) { wF[b] = 0.f; wB[b] = 0.f; cnt[b] = 0; }

    // pass 0: column min/max
    float mn = 3.0e38f, mx = -3.0e38f;
    for (int s = tid; s < S; s += 256) {
        float v = col[s];
        mn = fminf(mn, v); mx = fmaxf(mx, v);
    }
    for (int off = 32; off > 0; off >>= 1) {
        mn = fminf(mn, __shfl_down(mn, off, 64));
        mx = fmaxf(mx, __shfl_down(mx, off, 64));
    }
    if (lane == 0) { mnSh[wid] = mn; mxSh[wid] = mx; }
    __syncthreads();
    mn = fminf(fminf(mnSh[0], mnSh[1]), fminf(mnSh[2], mnSh[3]));
    mx = fmaxf(fmaxf(mxSh[0], mxSh[1]), fmaxf(mxSh[2], mxSh[3]));
    const float scale = (float)NB / fmaxf(mx - mn, 1e-20f);

    // pass A: bucket counts + flagged weight histograms
    for (int s = tid; s < S; s += 256) {
        float v  = col[s];
        int   tl = tlp[s];
        int   ts = tl & 0xffff;
        int   lb = tl >> 16;
        int   b  = (int)((v - mn) * scale); b = b > NB - 1 ? NB - 1 : b;
        atomicAdd(&cnt[b], 1);
        bool fF = (ts > tau) || (ts == tau && lb == 0);
        bool fB = (lb == 1) && (ts <= tau);
        if (fF) atomicAdd(&wF[b], __expf(v * INV_SIGMA));
        if (fB) atomicAdd(&wB[b], __expf(-v * INV_SIGMA));
    }
    __syncthreads();

    // scans: cnt -> offs (exclusive prefix, offs[NB]=S);
    //        wF -> strict suffix sums in place; wB -> strict prefix in place.
    {
        // int scan
        int base = tid * 4;
        int v0 = cnt[base], v1 = cnt[base + 1], v2 = cnt[base + 2], v3 = cnt[base + 3];
        int s1 = v0 + v1, s2 = s1 + v2, s3 = s2 + v3;
        int winc = s3;
        for (int off = 1; off < 64; off <<= 1) {
            int n = __shfl_up(winc, off, 64);
            if (lane >= off) winc += n;
        }
        if (lane == 63) wshi[wid] = winc;
        __syncthreads();
        int woff = 0, tot = 0;
        for (int w = 0; w < 4; ++w) { int x = wshi[w]; tot += x; if (w < wid) woff += x; }
        int te = woff + winc - s3;
        offs[base] = te; offs[base + 1] = te + v0; offs[base + 2] = te + s1; offs[base + 3] = te + s2;
        if (tid == 0) offs[NB] = tot;
        __syncthreads();
    }
    {
        // float scan of wF: strict suffix in place
        int base = tid * 4;
        float v0 = wF[base], v1 = wF[base + 1], v2 = wF[base + 2], v3 = wF[base + 3];
        float s0 = v0, s1 = s0 + v1, s2 = s1 + v2, s3 = s2 + v3;
        float winc = s3;
        for (int off = 1; off < 64; off <<= 1) {
            float n = __shfl_up(winc, off, 64);
            if (lane >= off) winc += n;
        }
        if (lane == 63) wshf[wid] = winc;
        __syncthreads();
        float woff = 0.f, tot = 0.f;
        for (int w = 0; w < 4; ++w) { float x = wshf[w]; tot += x; if (w < wid) woff += x; }
        float te = woff + winc - s3;
        wF[base] = tot - te - s0; wF[base + 1] = tot - te - s1;
        wF[base + 2] = tot - te - s2; wF[base + 3] = tot - te - s3;
        __syncthreads();
    }
    {
        // float scan of wB: strict (exclusive) prefix in place
        int base = tid * 4;
        float v0 = wB[base], v1 = wB[base + 1], v2 = wB[base + 2], v3 = wB[base + 3];
        float s0 = v0, s1 = s0 + v1, s2 = s1 + v2, s3 = s2 + v3;
        float winc = s3;
        for (int off = 1; off < 64; off <<= 1) {
            float n = __shfl_up(winc, off, 64);
            if (lane >= off) winc += n;
        }
        if (lane == 63) wshf[wid] = winc;
        __syncthreads();
        float woff = 0.f;
        for (int w = 0; w < wid; ++w) woff += wshf[w];
        float te = woff + winc - s3;
        wB[base] = te; wB[base + 1] = te + s0; wB[base + 2] = te + s1; wB[base + 3] = te + s2;
        __syncthreads();
    }

    // cursor init (reuse cnt)
    for (int b = tid; b < NB; b += 256) cnt[b] = offs[b];
    __syncthreads();

    // pass B: scatter (counting sort by bucket)
    for (int s = tid; s < S; s += 256) {
        float v  = col[s];
        int   tl = tlp[s];
        int   b  = (int)((v - mn) * scale); b = b > NB - 1 ? NB - 1 : b;
        int slot = atomicAdd(&cnt[b], 1);
        sortedV[slot] = v;
        sortedM[slot] = (unsigned char)((tl & 0x7f) | ((tl >> 16) << 7));
    }
    __syncthreads();

    // pass C: queries
    float sum = 0.f;
    for (int k = tid; k < S; k += 256) {
        int tl = tlp[k];
        int tk = tl & 0xffff;
        int lk = tl >> 16;

        if (lk == 1 && tk == tau) {          // forward query at column tau
            float vk = col[k];
            int b = (int)((vk - mn) * scale); b = b > NB - 1 ? NB - 1 : b;
            float acc = wF[b];               // exact: all buckets > b
            int e = offs[b + 1];
            for (int m = offs[b]; m < e; ++m) {
                float vm = sortedV[m];
                if (vm > vk) {
                    int mm = sortedM[m];
                    int tm = mm & 0x7f, lm = mm >> 7;
                    if ((tm > tau) || (tm == tau && lm == 0)) acc += __expf(vm * INV_SIGMA);
                }
            }
            sum += __expf(-vk * INV_SIGMA) * acc;
        }

        if (tk > 0) {                        // backward query if cb_k == tau
            int cb = lk ? tk - 1 : tk;
            if (cb == tau) {
                float vk = col[k];
                int b = (int)((vk - mn) * scale); b = b > NB - 1 ? NB - 1 : b;
                float acc = wB[b];           // exact: all buckets < b
                int e = offs[b + 1];
                for (int m = offs[b]; m < e; ++m) {
                    float vm = sortedV[m];
                    if (vm < vk) {
                        int mm = sortedM[m];
                        int tm = mm & 0x7f, lm = mm >> 7;
                        if (lm == 1 && tm <= tau) acc += __expf(-vm * INV_SIGMA);
                    }
                }
                sum += __expf(vk * INV_SIGMA) * acc;
            }
        }
    }

    // block reduction
    for (int off = 32; off > 0; off >>= 1) sum += __shfl_down(sum, off, 64);
    __syncthreads();                          // protect wshf reuse
    if (lane == 0) wshf[wid] = sum;
    __syncthreads();
    if (tid == 0) partials[bx] = wshf[0] + wshf[1] + wshf[2] + wshf[3];
}

// ---------------------------------------------------------------------------
// Kernel 3: final reduction -> out[0] = ALPHA * total
// ---------------------------------------------------------------------------
__global__ __launch_bounds__(256) void reduce_kernel(
    const float* __restrict__ partials, int n, float* __restrict__ out)
{
    float sum = 0.f;
    for (int idx = threadIdx.x; idx < n; idx += 256) sum += partials[idx];
    for (int off = 32; off > 0; off >>= 1) sum += __shfl_down(sum, off, 64);
    __shared__ float wsum[4];
    const int lane = threadIdx.x & 63;
    const int wid  = threadIdx.x >> 6;
    if (lane == 0) wsum[wid] = sum;
    __syncthreads();
    if (threadIdx.x == 0)
        out[0] = ALPHA_C * (wsum[0] + wsum[1] + wsum[2] + wsum[3]);
}

extern "C" void kernel_launch(void* const* d_in, const int* in_sizes, int n_in,
                              void* d_out, int out_size, void* d_ws, size_t ws_size,
                              hipStream_t stream)
{
    const float* event_out = (const float*)d_in[0];  // (E,S,T) fp32
    const int*   et        = (const int*)d_in[1];    // (S,E) int32
    const int*   labsp     = (const int*)d_in[2];    // (S,E) int32
    const int S = in_sizes[1] / E_CONST;             // 8192

    float* cumT = (float*)d_ws;                                   // E*T*S floats
    int*   tlA  = (int*)(cumT + (size_t)E_CONST * T_CONST * S);   // E*S
    float* partials = (float*)(tlA + (size_t)E_CONST * S);        // E*T

    const int prepBlocks = E_CONST * (S / 64);
    hipLaunchKernelGGL(prep_kernel, dim3(prepBlocks), dim3(64), 0, stream,
                       event_out, et, labsp, cumT, tlA, S);

    const int nB = E_CONST * T_CONST;
    hipLaunchKernelGGL(bucket_kernel, dim3(nB), dim3(256), 0, stream,
                       cumT, tlA, partials, S);

    hipLaunchKernelGGL(reduce_kernel, dim3(1), dim3(256), 0, stream,
                       partials, nB, (float*)d_out);
}

// Round 3
// 178.178 us; speedup vs baseline: 3.9047x; 3.9047x over previous
//
#include <hip/hip_runtime.h>

#define E_CONST 3
#define T_CONST 100
#define C10 10.0f
#define ALPHA_C 0.05f
#define NEGBIG -1.0e38f

// ---------------------------------------------------------------------------
// prep: per-(i,s) cumsum over T -> transposed cumT[i][tau][s], plus per-k
// metadata vf/vb/tl (vf/vb used only by the fallback path; cheap).
// ---------------------------------------------------------------------------
__global__ __launch_bounds__(64) void prep_kernel(
    const float* __restrict__ event_out, const int* __restrict__ et,
    const int* __restrict__ labs, float* __restrict__ cumT,
    float* __restrict__ vfA, float* __restrict__ vbA, int* __restrict__ tlA,
    int S)
{
    __shared__ float tile[64][T_CONST + 1];
    const int tilesPerEvent = S / 64;
    const int i  = blockIdx.x / tilesPerEvent;
    const int s0 = (blockIdx.x % tilesPerEvent) * 64;
    const int tid = threadIdx.x;

    const float* src = event_out + ((size_t)i * S + s0) * T_CONST;
    for (int idx = tid; idx < 64 * T_CONST; idx += 64) {
        int row = idx / T_CONST;
        int col = idx - row * T_CONST;
        tile[row][col] = src[idx];
    }
    __syncthreads();

    float run = 0.f;
    for (int tau = 0; tau < T_CONST; ++tau) {
        run += tile[tid][tau];
        tile[tid][tau] = run;
    }
    __syncthreads();

    float* dst = cumT + (size_t)i * T_CONST * S + s0;
    for (int idx = tid; idx < 64 * T_CONST; idx += 64) {
        int tau = idx >> 6;
        int sl  = idx & 63;
        dst[(size_t)tau * S + sl] = tile[sl][tau];
    }

    const int s   = s0 + tid;
    const int t   = et[s * E_CONST + i];
    const int lab = labs[s * E_CONST + i];
    const float vf = tile[tid][t];
    const int   cb = lab ? (t > 0 ? t - 1 : 0) : t;
    const float vb = tile[tid][cb];
    const int base = i * S + s;
    vfA[base] = vf;
    vbA[base] = vb;
    tlA[base] = (t & 0xffff) | (lab << 16);
}

// ---------------------------------------------------------------------------
// meta: per event, counting-sort s by key=(t, lab1-first) -> perm;
// lab1-only sorted by t -> permB; boundary tables fstartA (start of lab0
// group of bin tau) and b1endA (inclusive count of lab1 with t<=tau).
// ---------------------------------------------------------------------------
__global__ __launch_bounds__(256) void meta_kernel(
    const int* __restrict__ et, const int* __restrict__ labs,
    int* __restrict__ perm, int* __restrict__ permB,
    int* __restrict__ fstartA, int* __restrict__ b1endA, int S)
{
    __shared__ int histK[2 * T_CONST];
    __shared__ int histB[T_CONST];
    __shared__ int startK[2 * T_CONST];
    __shared__ int startB[T_CONST];
    const int i = blockIdx.x;
    const int tid = threadIdx.x;

    for (int b = tid; b < 2 * T_CONST; b += 256) histK[b] = 0;
    for (int b = tid; b < T_CONST; b += 256) histB[b] = 0;
    __syncthreads();

    for (int s = tid; s < S; s += 256) {
        int t = et[s * E_CONST + i];
        int lab = labs[s * E_CONST + i];
        atomicAdd(&histK[t * 2 + (1 - lab)], 1);
        if (lab) atomicAdd(&histB[t], 1);
    }
    __syncthreads();

    if (tid == 0) {
        int acc = 0;
        for (int b = 0; b < 2 * T_CONST; ++b) { startK[b] = acc; acc += histK[b]; }
        acc = 0;
        for (int b = 0; b < T_CONST; ++b) { startB[b] = acc; acc += histB[b]; }
    }
    __syncthreads();

    if (tid < T_CONST) {
        fstartA[i * T_CONST + tid] = startK[2 * tid + 1];
        b1endA[i * T_CONST + tid]  = startB[tid] + histB[tid];  // inclusive
    }
    __syncthreads();

    // reuse hists as scatter cursors
    for (int b = tid; b < 2 * T_CONST; b += 256) histK[b] = startK[b];
    for (int b = tid; b < T_CONST; b += 256) histB[b] = startB[b];
    __syncthreads();

    for (int s = tid; s < S; s += 256) {
        int t = et[s * E_CONST + i];
        int lab = labs[s * E_CONST + i];
        int slot = atomicAdd(&histK[t * 2 + (1 - lab)], 1);
        perm[i * S + slot] = s;
        if (lab) {
            int sb = atomicAdd(&histB[t], 1);
            permB[i * S + sb] = s;
        }
    }
}

// ---------------------------------------------------------------------------
// permute: colPerm[i][tau][j] = cumT[i][tau][perm[j]];
//          colPermB[i][tau][jb] = cumT[i][tau][permB[jb]] (jb < n1).
// grid (E*T, 4); gathers stay within one 32KB column -> L1/L2 friendly.
// ---------------------------------------------------------------------------
__global__ __launch_bounds__(256) void permute_kernel(
    const float* __restrict__ cumT, const int* __restrict__ perm,
    const int* __restrict__ permB, const int* __restrict__ b1endA,
    float* __restrict__ colPerm, float* __restrict__ colPermB, int S)
{
    const int colIdx = blockIdx.x;            // i*T + tau
    const int i = colIdx / T_CONST;
    const float* __restrict__ col = cumT + (size_t)colIdx * S;
    const int n1 = b1endA[i * T_CONST + T_CONST - 1];
    const int chunk = (2 * S) / 4;
    const int beg = blockIdx.y * chunk;
    const int end = beg + chunk;
    for (int idx = beg + (int)threadIdx.x; idx < end; idx += 256) {
        if (idx < S) {
            colPerm[(size_t)colIdx * S + idx] = col[perm[i * S + idx]];
        } else {
            int jb = idx - S;
            if (jb < n1)
                colPermB[(size_t)colIdx * S + jb] = col[permB[i * S + jb]];
        }
    }
}

// ---------------------------------------------------------------------------
// pair2: one block per (i, j) where j indexes perm order (groups queries by
// column for L2 locality). Forward: contiguous suffix [fstart(tk), S) of
// colPerm[tk]; Backward: contiguous prefix [0, b1end(cb)) of colPermB[cb].
// Branchless hot loop: fma + cmp/sel + __expf (sel -> -1e38 -> exp = 0).
// ---------------------------------------------------------------------------
__global__ __launch_bounds__(256) void pair2_kernel(
    const float* __restrict__ cumT, const float* __restrict__ colPerm,
    const float* __restrict__ colPermB, const int* __restrict__ tlA,
    const int* __restrict__ perm, const int* __restrict__ fstartA,
    const int* __restrict__ b1endA, float* __restrict__ partials, int S)
{
    const int bx = blockIdx.x;
    const int i  = bx / S;
    const int j  = bx - i * S;
    const int tid = threadIdx.x;
    const int k  = perm[i * S + j];
    const int tl = tlA[i * S + k];
    const int tk = tl & 0xffff;
    const int lk = tl >> 16;

    float sum = 0.f;

    if (lk) {  // forward term at column tk
        const size_t cbase = ((size_t)i * T_CONST + tk) * S;
        const float* __restrict__ cp = colPerm + cbase;
        const float vk = cumT[cbase + k];
        const float bb = -vk * C10;
        const int lo  = fstartA[i * T_CONST + tk];
        const int loa = (lo + 3) & ~3;           // <= S (S % 4 == 0)
        if (tid < loa - lo) {
            float f = fmaf(cp[lo + tid], C10, bb);
            sum += __expf(f > 0.f ? f : NEGBIG);
        }
        for (int p = loa + tid * 4; p < S; p += 1024) {
            const float4 v = *reinterpret_cast<const float4*>(cp + p);
            float f0 = fmaf(v.x, C10, bb); sum += __expf(f0 > 0.f ? f0 : NEGBIG);
            float f1 = fmaf(v.y, C10, bb); sum += __expf(f1 > 0.f ? f1 : NEGBIG);
            float f2 = fmaf(v.z, C10, bb); sum += __expf(f2 > 0.f ? f2 : NEGBIG);
            float f3 = fmaf(v.w, C10, bb); sum += __expf(f3 > 0.f ? f3 : NEGBIG);
        }
    }

    if (tk > 0) {  // backward term at column cb
        const int cb = lk ? tk - 1 : tk;
        const size_t cbase = ((size_t)i * T_CONST + cb) * S;
        const float* __restrict__ cp = colPermB + cbase;
        const float vk = cumT[cbase + k];
        const float bb = vk * C10;
        const int hi  = b1endA[i * T_CONST + cb];
        const int hia = hi & ~3;
        for (int p = tid * 4; p < hia; p += 1024) {
            const float4 v = *reinterpret_cast<const float4*>(cp + p);
            float f0 = fmaf(v.x, -C10, bb); sum += __expf(f0 > 0.f ? f0 : NEGBIG);
            float f1 = fmaf(v.y, -C10, bb); sum += __expf(f1 > 0.f ? f1 : NEGBIG);
            float f2 = fmaf(v.z, -C10, bb); sum += __expf(f2 > 0.f ? f2 : NEGBIG);
            float f3 = fmaf(v.w, -C10, bb); sum += __expf(f3 > 0.f ? f3 : NEGBIG);
        }
        if (tid < hi - hia) {
            float f = fmaf(cp[hia + tid], -C10, bb);
            sum += __expf(f > 0.f ? f : NEGBIG);
        }
    }

    for (int off = 32; off > 0; off >>= 1) sum += __shfl_down(sum, off, 64);
    __shared__ float wsum[4];
    const int lane = tid & 63, wid = tid >> 6;
    if (lane == 0) wsum[wid] = sum;
    __syncthreads();
    if (tid == 0) partials[bx] = wsum[0] + wsum[1] + wsum[2] + wsum[3];
}

// ---------------------------------------------------------------------------
// fallback pair kernel (R1, proven): used only if ws_size is too small.
// ---------------------------------------------------------------------------
__global__ __launch_bounds__(256) void pair_kernel(
    const float* __restrict__ cumT, const float* __restrict__ vfA,
    const float* __restrict__ vbA, const int* __restrict__ tlA,
    float* __restrict__ partials, int S)
{
    const int bx = blockIdx.x;
    const int i  = bx / S;
    const int k  = bx - i * S;
    const int base = i * S;
    const int tlk = tlA[base + k];
    const int t_k = tlk & 0xffff;
    const int lab_k = tlk >> 16;
    const bool doF = (lab_k == 1);
    const bool doB = (t_k > 0);
    float sum = 0.f;
    if (doF || doB) {
        const float vf_k = vfA[base + k];
        const float vb_k = vbA[base + k];
        const int cb = lab_k ? (t_k > 0 ? t_k - 1 : 0) : t_k;
        const float* __restrict__ colF = cumT + ((size_t)i * T_CONST + t_k) * S;
        const float* __restrict__ colB = cumT + ((size_t)i * T_CONST + cb)  * S;
        const int* __restrict__ tlp = tlA + base;
        for (int s = threadIdx.x; s < S; s += 256) {
            const int tls = tlp[s];
            const int t_s = tls & 0xffff;
            const int lab_s = tls >> 16;
            if (doF) {
                const float vs = colF[s];
                const bool c = (t_s > t_k) | ((t_s == t_k) & (lab_s == 0));
                if (c & (vs > vf_k)) sum += __expf((vs - vf_k) * C10);
            }
            if (doB) {
                const float vs = colB[s];
                const bool c = (t_s <= cb) & (lab_s == 1);
                if (c & (vb_k > vs)) sum += __expf((vb_k - vs) * C10);
            }
        }
    }
    for (int off = 32; off > 0; off >>= 1) sum += __shfl_down(sum, off, 64);
    __shared__ float wsum[4];
    const int lane = threadIdx.x & 63, wid = threadIdx.x >> 6;
    if (lane == 0) wsum[wid] = sum;
    __syncthreads();
    if (threadIdx.x == 0) partials[bx] = wsum[0] + wsum[1] + wsum[2] + wsum[3];
}

__global__ __launch_bounds__(256) void reduce_kernel(
    const float* __restrict__ partials, int n, float* __restrict__ out)
{
    float sum = 0.f;
    for (int idx = threadIdx.x; idx < n; idx += 256) sum += partials[idx];
    for (int off = 32; off > 0; off >>= 1) sum += __shfl_down(sum, off, 64);
    __shared__ float wsum[4];
    const int lane = threadIdx.x & 63, wid = threadIdx.x >> 6;
    if (lane == 0) wsum[wid] = sum;
    __syncthreads();
    if (threadIdx.x == 0)
        out[0] = ALPHA_C * (wsum[0] + wsum[1] + wsum[2] + wsum[3]);
}

extern "C" void kernel_launch(void* const* d_in, const int* in_sizes, int n_in,
                              void* d_out, int out_size, void* d_ws, size_t ws_size,
                              hipStream_t stream)
{
    const float* event_out = (const float*)d_in[0];  // (E,S,T) fp32
    const int*   et        = (const int*)d_in[1];    // (S,E) int32
    const int*   labsp     = (const int*)d_in[2];    // (S,E) int32
    const int S = in_sizes[1] / E_CONST;             // 8192

    const size_t colElems = (size_t)E_CONST * T_CONST * S;  // 2,457,600
    const size_t esElems  = (size_t)E_CONST * S;

    char* p = (char*)d_ws;
    float* cumT     = (float*)p; p += colElems * 4;
    float* colPerm  = (float*)p; p += colElems * 4;
    float* colPermB = (float*)p; p += colElems * 4;
    float* vfA      = (float*)p; p += esElems * 4;
    float* vbA      = (float*)p; p += esElems * 4;
    int*   tlA      = (int*)p;   p += esElems * 4;
    int*   perm     = (int*)p;   p += esElems * 4;
    int*   permB    = (int*)p;   p += esElems * 4;
    float* partials = (float*)p; p += esElems * 4;
    int*   fstartA  = (int*)p;   p += 4096;
    int*   b1endA   = (int*)p;   p += 4096;
    const size_t needed = (size_t)(p - (char*)d_ws);

    const int prepBlocks = E_CONST * (S / 64);
    hipLaunchKernelGGL(prep_kernel, dim3(prepBlocks), dim3(64), 0, stream,
                       event_out, et, labsp, cumT, vfA, vbA, tlA, S);

    const int nB = E_CONST * S;
    if (ws_size >= needed) {
        hipLaunchKernelGGL(meta_kernel, dim3(E_CONST), dim3(256), 0, stream,
                           et, labsp, perm, permB, fstartA, b1endA, S);
        hipLaunchKernelGGL(permute_kernel, dim3(E_CONST * T_CONST, 4), dim3(256), 0, stream,
                           cumT, perm, permB, b1endA, colPerm, colPermB, S);
        hipLaunchKernelGGL(pair2_kernel, dim3(nB), dim3(256), 0, stream,
                           cumT, colPerm, colPermB, tlA, perm, fstartA, b1endA,
                           partials, S);
    } else {
        hipLaunchKernelGGL(pair_kernel, dim3(nB), dim3(256), 0, stream,
                           cumT, vfA, vbA, tlA, partials, S);
    }
    hipLaunchKernelGGL(reduce_kernel, dim3(1), dim3(256), 0, stream,
                       partials, nB, (float*)d_out);
}

// Round 4
// 150.743 us; speedup vs baseline: 4.6153x; 1.1820x over previous
//
#include <hip/hip_runtime.h>

#define E_CONST 3
#define T_CONST 100
#define C10 10.0f
#define ALPHA_C 0.05f

// ---------------------------------------------------------------------------
// prep: one thread per (i,s) row. Register cumsum over T=100 via float4 row
// loads (rows are 400B, 16B-aligned); transposed coalesced stores to
// cumT[i][tau][s]. Fuses metadata write + global histogram atomics.
// ---------------------------------------------------------------------------
__global__ __launch_bounds__(64) void prep_kernel(
    const float* __restrict__ event_out, const int* __restrict__ et,
    const int* __restrict__ labs, float* __restrict__ cumT,
    int* __restrict__ tlA, int* __restrict__ histK, int* __restrict__ histB,
    int S)
{
    const int gid = blockIdx.x * 64 + threadIdx.x;   // 0 .. E*S-1
    const int i = gid / S;
    const int s = gid - i * S;
    const float4* __restrict__ row =
        reinterpret_cast<const float4*>(event_out + (size_t)gid * T_CONST);
    float* __restrict__ base = cumT + (size_t)i * T_CONST * S + s;

    float run = 0.f;
    #pragma unroll
    for (int c = 0; c < T_CONST / 4; ++c) {
        const float4 v = row[c];
        const float c0 = run + v.x;
        const float c1 = c0 + v.y;
        const float c2 = c1 + v.z;
        const float c3 = c2 + v.w;
        base[(size_t)(4 * c + 0) * S] = c0;
        base[(size_t)(4 * c + 1) * S] = c1;
        base[(size_t)(4 * c + 2) * S] = c2;
        base[(size_t)(4 * c + 3) * S] = c3;
        run = c3;
    }

    const int t   = et[s * E_CONST + i];
    const int lab = labs[s * E_CONST + i];
    tlA[i * S + s] = (t & 0xffff) | (lab << 16);
    atomicAdd(&histK[i * 2 * T_CONST + t * 2 + (1 - lab)], 1);
    if (lab) atomicAdd(&histB[i * T_CONST + t], 1);
}

// ---------------------------------------------------------------------------
// scan: per event, exclusive-prefix the 200-bin key histogram and the 100-bin
// lab1 histogram; emit scatter cursors + fstart (start of lab0 group of bin
// tau) + b1end (inclusive lab1 count with t<=tau). Tiny (3 blocks) but O(200).
// ---------------------------------------------------------------------------
__global__ __launch_bounds__(256) void scan_kernel(
    const int* __restrict__ histK, const int* __restrict__ histB,
    int* __restrict__ cursK, int* __restrict__ cursB,
    int* __restrict__ fstartA, int* __restrict__ b1endA)
{
    __shared__ int sK[2 * T_CONST];
    __shared__ int sB[T_CONST];
    const int i = blockIdx.x, tid = threadIdx.x;
    if (tid == 0) {
        int acc = 0;
        for (int b = 0; b < 2 * T_CONST; ++b) { sK[b] = acc; acc += histK[i * 2 * T_CONST + b]; }
        acc = 0;
        for (int b = 0; b < T_CONST; ++b) { sB[b] = acc; acc += histB[i * T_CONST + b]; }
    }
    __syncthreads();
    if (tid < 2 * T_CONST) cursK[i * 2 * T_CONST + tid] = sK[tid];
    if (tid < T_CONST) {
        cursB[i * T_CONST + tid]   = sB[tid];
        fstartA[i * T_CONST + tid] = sK[2 * tid + 1];
        b1endA[i * T_CONST + tid]  = sB[tid] + histB[i * T_CONST + tid];
    }
}

// ---------------------------------------------------------------------------
// scatter: one thread per (i,s); counting-sort via global atomic cursors.
// perm: sorted by key (t, lab1-first). permB: lab1 only, sorted by t.
// ---------------------------------------------------------------------------
__global__ __launch_bounds__(256) void scatter_kernel(
    const int* __restrict__ tlA, int* __restrict__ cursK, int* __restrict__ cursB,
    int* __restrict__ perm, int* __restrict__ permB, int S)
{
    const int gid = blockIdx.x * 256 + threadIdx.x;
    const int i = gid / S;
    const int s = gid - i * S;
    const int tl = tlA[i * S + s];
    const int t = tl & 0xffff, lab = tl >> 16;
    const int slot = atomicAdd(&cursK[i * 2 * T_CONST + t * 2 + (1 - lab)], 1);
    perm[i * S + slot] = s;
    if (lab) {
        const int sb = atomicAdd(&cursB[i * T_CONST + t], 1);
        permB[i * S + sb] = s;
    }
}

// ---------------------------------------------------------------------------
// permute+exp: expF[i][tau][j] = exp(10*cumT[i][tau][perm[j]]);
//              expB[i][tau][jb] = exp(-10*cumT[i][tau][permB[jb]]), jb < n1.
// cum in (0,1] so expF in (1, e^10], expB in [e^-10, 1) — no overflow.
// ---------------------------------------------------------------------------
__global__ __launch_bounds__(256) void permute_kernel(
    const float* __restrict__ cumT, const int* __restrict__ perm,
    const int* __restrict__ permB, const int* __restrict__ b1endA,
    float* __restrict__ expF, float* __restrict__ expB, int S)
{
    const int colIdx = blockIdx.x;            // i*T + tau
    const int i = colIdx / T_CONST;
    const float* __restrict__ col = cumT + (size_t)colIdx * S;
    const int n1 = b1endA[i * T_CONST + T_CONST - 1];
    const int chunk = (2 * S) / 8;
    const int beg = blockIdx.y * chunk;
    const int end = beg + chunk;
    for (int idx = beg + (int)threadIdx.x; idx < end; idx += 256) {
        if (idx < S) {
            expF[(size_t)colIdx * S + idx] = __expf(C10 * col[perm[i * S + idx]]);
        } else {
            const int jb = idx - S;
            if (jb < n1)
                expB[(size_t)colIdx * S + jb] = __expf(-C10 * col[permB[i * S + jb]]);
        }
    }
}

// ---------------------------------------------------------------------------
// pair2: one block per (i,j) in perm order (consecutive blocks share columns
// -> L2 locality). Monotonicity of exp lets the hot loop be pure
// load/cmp/select/add — no transcendentals:
//   fwd:  sum of e_s=exp(10 v_s) over suffix [fstart(tk),S) with e_s > e_k,
//         scaled by 1/e_k.
//   bwd:  sum of eb_s=exp(-10 v_s) over prefix [0,b1end(cb)) with eb_s > 1/e_k,
//         scaled by e_k.
// Self-exclusion automatic (strict compare / range).
// ---------------------------------------------------------------------------
__global__ __launch_bounds__(256) void pair2_kernel(
    const float* __restrict__ expF, const float* __restrict__ expB,
    const int* __restrict__ tlA, const int* __restrict__ perm,
    const int* __restrict__ fstartA, const int* __restrict__ b1endA,
    float* __restrict__ partials, int S)
{
    const int bx = blockIdx.x;
    const int i = bx / S;
    const int j = bx - i * S;
    const int tid = threadIdx.x;
    const int k = perm[i * S + j];
    const int tl = tlA[i * S + k];
    const int tk = tl & 0xffff;
    const int lk = tl >> 16;

    float total = 0.f;

    if (lk) {  // forward term at column tk
        const size_t cbase = ((size_t)i * T_CONST + tk) * S;
        const float* __restrict__ cp = expF + cbase;
        const float thr = cp[j];                       // e_k = exp(10 v_k)
        const int lo  = fstartA[i * T_CONST + tk];
        const int loa = (lo + 3) & ~3;
        float sum = 0.f;
        if (tid < loa - lo) { const float e = cp[lo + tid]; sum += (e > thr) ? e : 0.f; }
        for (int p = loa + tid * 4; p < S; p += 1024) {
            const float4 v = *reinterpret_cast<const float4*>(cp + p);
            sum += (v.x > thr) ? v.x : 0.f;
            sum += (v.y > thr) ? v.y : 0.f;
            sum += (v.z > thr) ? v.z : 0.f;
            sum += (v.w > thr) ? v.w : 0.f;
        }
        total += sum * (1.0f / thr);
    }

    if (tk > 0) {  // backward term at column cb
        const int cb = lk ? tk - 1 : tk;
        const size_t cbase = ((size_t)i * T_CONST + cb) * S;
        const float efk = expF[cbase + j];             // exp(10 v_k) at col cb
        const float thr = 1.0f / efk;                  // exp(-10 v_k)
        const float* __restrict__ cp = expB + cbase;
        const int hi  = b1endA[i * T_CONST + cb];
        const int hia = hi & ~3;
        float sum = 0.f;
        for (int p = tid * 4; p < hia; p += 1024) {
            const float4 v = *reinterpret_cast<const float4*>(cp + p);
            sum += (v.x > thr) ? v.x : 0.f;
            sum += (v.y > thr) ? v.y : 0.f;
            sum += (v.z > thr) ? v.z : 0.f;
            sum += (v.w > thr) ? v.w : 0.f;
        }
        if (tid < hi - hia) { const float e = cp[hia + tid]; sum += (e > thr) ? e : 0.f; }
        total += sum * efk;
    }

    for (int off = 32; off > 0; off >>= 1) total += __shfl_down(total, off, 64);
    __shared__ float wsum[4];
    const int lane = tid & 63, wid = tid >> 6;
    if (lane == 0) wsum[wid] = total;
    __syncthreads();
    if (tid == 0) partials[bx] = wsum[0] + wsum[1] + wsum[2] + wsum[3];
}

// ---------------------------------------------------------------------------
// fallback (R1-proven structure): used only if ws_size is too small.
// ---------------------------------------------------------------------------
__global__ __launch_bounds__(256) void pair_kernel(
    const float* __restrict__ cumT, const int* __restrict__ tlA,
    float* __restrict__ partials, int S)
{
    const int bx = blockIdx.x;
    const int i = bx / S;
    const int k = bx - i * S;
    const int base = i * S;
    const int tlk = tlA[base + k];
    const int t_k = tlk & 0xffff;
    const int lab_k = tlk >> 16;
    const bool doF = (lab_k == 1);
    const bool doB = (t_k > 0);
    float sum = 0.f;
    if (doF || doB) {
        const int cb = lab_k ? (t_k > 0 ? t_k - 1 : 0) : t_k;
        const float* __restrict__ colF = cumT + ((size_t)i * T_CONST + t_k) * S;
        const float* __restrict__ colB = cumT + ((size_t)i * T_CONST + cb)  * S;
        const float vf_k = colF[k];
        const float vb_k = colB[k];
        const int* __restrict__ tlp = tlA + base;
        for (int s = threadIdx.x; s < S; s += 256) {
            const int tls = tlp[s];
            const int t_s = tls & 0xffff;
            const int lab_s = tls >> 16;
            if (doF) {
                const float vs = colF[s];
                const bool c = (t_s > t_k) | ((t_s == t_k) & (lab_s == 0));
                if (c & (vs > vf_k)) sum += __expf((vs - vf_k) * C10);
            }
            if (doB) {
                const float vs = colB[s];
                const bool c = (t_s <= cb) & (lab_s == 1);
                if (c & (vb_k > vs)) sum += __expf((vb_k - vs) * C10);
            }
        }
    }
    for (int off = 32; off > 0; off >>= 1) sum += __shfl_down(sum, off, 64);
    __shared__ float wsum[4];
    const int lane = threadIdx.x & 63, wid = threadIdx.x >> 6;
    if (lane == 0) wsum[wid] = sum;
    __syncthreads();
    if (threadIdx.x == 0) partials[bx] = wsum[0] + wsum[1] + wsum[2] + wsum[3];
}

__global__ __launch_bounds__(1024) void reduce_kernel(
    const float* __restrict__ partials, int n, float* __restrict__ out)
{
    float sum = 0.f;
    for (int idx = threadIdx.x; idx < n; idx += 1024) sum += partials[idx];
    for (int off = 32; off > 0; off >>= 1) sum += __shfl_down(sum, off, 64);
    __shared__ float wsum[16];
    const int lane = threadIdx.x & 63, wid = threadIdx.x >> 6;
    if (lane == 0) wsum[wid] = sum;
    __syncthreads();
    if (threadIdx.x == 0) {
        float t = 0.f;
        for (int w = 0; w < 16; ++w) t += wsum[w];
        out[0] = ALPHA_C * t;
    }
}

extern "C" void kernel_launch(void* const* d_in, const int* in_sizes, int n_in,
                              void* d_out, int out_size, void* d_ws, size_t ws_size,
                              hipStream_t stream)
{
    const float* event_out = (const float*)d_in[0];  // (E,S,T) fp32
    const int*   et        = (const int*)d_in[1];    // (S,E) int32
    const int*   labsp     = (const int*)d_in[2];    // (S,E) int32
    const int S = in_sizes[1] / E_CONST;             // 8192

    const size_t colElems = (size_t)E_CONST * T_CONST * S;
    const size_t esElems  = (size_t)E_CONST * S;

    char* p = (char*)d_ws;
    float* cumT     = (float*)p; p += colElems * 4;
    float* expF     = (float*)p; p += colElems * 4;
    float* expB     = (float*)p; p += colElems * 4;
    int*   tlA      = (int*)p;   p += esElems * 4;
    int*   perm     = (int*)p;   p += esElems * 4;
    int*   permB    = (int*)p;   p += esElems * 4;
    float* partials = (float*)p; p += esElems * 4;
    int*   fstartA  = (int*)p;   p += E_CONST * T_CONST * 4;
    int*   b1endA   = (int*)p;   p += E_CONST * T_CONST * 4;
    int*   histK    = (int*)p;   p += E_CONST * 2 * T_CONST * 4;
    int*   histB    = (int*)p;   p += E_CONST * T_CONST * 4;
    int*   cursK    = (int*)p;   p += E_CONST * 2 * T_CONST * 4;
    int*   cursB    = (int*)p;   p += E_CONST * T_CONST * 4;
    const size_t needed = (size_t)(p - (char*)d_ws);
    const size_t fallback_needed =
        colElems * 4 + esElems * 4 * 2;  // cumT + tlA + partials (re-laid)

    const int nB = E_CONST * S;

    if (ws_size >= needed) {
        // zero histograms (tiny, graph-capturable)
        hipMemsetAsync(histK, 0, (size_t)E_CONST * 3 * T_CONST * 4, stream);

        hipLaunchKernelGGL(prep_kernel, dim3(E_CONST * S / 64), dim3(64), 0, stream,
                           event_out, et, labsp, cumT, tlA, histK, histB, S);
        hipLaunchKernelGGL(scan_kernel, dim3(E_CONST), dim3(256), 0, stream,
                           histK, histB, cursK, cursB, fstartA, b1endA);
        hipLaunchKernelGGL(scatter_kernel, dim3(E_CONST * S / 256), dim3(256), 0, stream,
                           tlA, cursK, cursB, perm, permB, S);
        hipLaunchKernelGGL(permute_kernel, dim3(E_CONST * T_CONST, 8), dim3(256), 0, stream,
                           cumT, perm, permB, b1endA, expF, expB, S);
        hipLaunchKernelGGL(pair2_kernel, dim3(nB), dim3(256), 0, stream,
                           expF, expB, tlA, perm, fstartA, b1endA, partials, S);
        hipLaunchKernelGGL(reduce_kernel, dim3(1), dim3(1024), 0, stream,
                           partials, nB, (float*)d_out);
    } else if (ws_size >= fallback_needed) {
        float* cumT2     = (float*)d_ws;
        int*   tlA2      = (int*)(cumT2 + colElems);
        float* partials2 = (float*)(tlA2 + esElems);
        // prep without hists: reuse prep via dummy hist pointers inside cumT?
        // Simplest: run prep with hist pointers aimed at partials2 (overwritten
        // later by pair_kernel outputs) — atomics land in scratch, harmless.
        hipLaunchKernelGGL(prep_kernel, dim3(E_CONST * S / 64), dim3(64), 0, stream,
                           event_out, et, labsp, cumT2, tlA2,
                           (int*)partials2, (int*)partials2, S);
        hipLaunchKernelGGL(pair_kernel, dim3(nB), dim3(256), 0, stream,
                           cumT2, tlA2, partials2, S);
        hipLaunchKernelGGL(reduce_kernel, dim3(1), dim3(1024), 0, stream,
                           partials2, nB, (float*)d_out);
    }
}

// Round 5
// 147.315 us; speedup vs baseline: 4.7227x; 1.0233x over previous
//
#include <hip/hip_runtime.h>

#define E_CONST 3
#define T_CONST 100
#define C10 10.0f
#define ALPHA_C 0.05f

// ---------------------------------------------------------------------------
// prep: one thread per (i,s) row. Register cumsum over T=100 via float4 row
// loads; transposed coalesced stores to cumT[i][tau][s]. Fuses metadata write
// + global histogram atomics (histK: 200 bins/event, histB: 100 bins/event).
// ---------------------------------------------------------------------------
__global__ __launch_bounds__(64) void prep_kernel(
    const float* __restrict__ event_out, const int* __restrict__ et,
    const int* __restrict__ labs, float* __restrict__ cumT,
    int* __restrict__ tlA, int* __restrict__ histK, int* __restrict__ histB,
    int S)
{
    const int gid = blockIdx.x * 64 + threadIdx.x;   // 0 .. E*S-1
    const int i = gid / S;
    const int s = gid - i * S;
    const float4* __restrict__ row =
        reinterpret_cast<const float4*>(event_out + (size_t)gid * T_CONST);
    float* __restrict__ base = cumT + (size_t)i * T_CONST * S + s;

    float run = 0.f;
    #pragma unroll
    for (int c = 0; c < T_CONST / 4; ++c) {
        const float4 v = row[c];
        const float c0 = run + v.x;
        const float c1 = c0 + v.y;
        const float c2 = c1 + v.z;
        const float c3 = c2 + v.w;
        base[(size_t)(4 * c + 0) * S] = c0;
        base[(size_t)(4 * c + 1) * S] = c1;
        base[(size_t)(4 * c + 2) * S] = c2;
        base[(size_t)(4 * c + 3) * S] = c3;
        run = c3;
    }

    const int t   = et[s * E_CONST + i];
    const int lab = labs[s * E_CONST + i];
    tlA[i * S + s] = (t & 0xffff) | (lab << 16);
    atomicAdd(&histK[i * 2 * T_CONST + t * 2 + (1 - lab)], 1);
    if (lab) atomicAdd(&histB[i * T_CONST + t], 1);
}

__device__ inline int waveInclScan(int v, int lane) {
    #pragma unroll
    for (int off = 1; off < 64; off <<= 1) {
        int n = __shfl_up(v, off, 64);
        if (lane >= off) v += n;
    }
    return v;
}

// ---------------------------------------------------------------------------
// scan: per event, PARALLEL exclusive-prefix of the 200-bin key histogram and
// 100-bin lab1 histogram (one bin per thread, shuffle scan + cross-wave
// offsets). Emits scatter cursors, fstart (start of lab0 group of bin tau),
// b1end (inclusive lab1 count with t<=tau).
// ---------------------------------------------------------------------------
__global__ __launch_bounds__(256) void scan_kernel(
    const int* __restrict__ histK, const int* __restrict__ histB,
    int* __restrict__ cursK, int* __restrict__ cursB,
    int* __restrict__ fstartA, int* __restrict__ b1endA)
{
    const int i = blockIdx.x, tid = threadIdx.x;
    const int lane = tid & 63, wid = tid >> 6;
    __shared__ int wsumK[4], wsumB[4];

    const int vK = (tid < 2 * T_CONST) ? histK[i * 2 * T_CONST + tid] : 0;
    int inclK = waveInclScan(vK, lane);
    const int vB = (tid < T_CONST) ? histB[i * T_CONST + tid] : 0;
    int inclB = waveInclScan(vB, lane);
    if (lane == 63) { wsumK[wid] = inclK; wsumB[wid] = inclB; }
    __syncthreads();
    int offK = 0, offB = 0;
    for (int w = 0; w < wid; ++w) { offK += wsumK[w]; offB += wsumB[w]; }
    inclK += offK; inclB += offB;
    const int exclK = inclK - vK;
    const int exclB = inclB - vB;

    if (tid < 2 * T_CONST) {
        cursK[i * 2 * T_CONST + tid] = exclK;
        if (tid & 1) fstartA[i * T_CONST + (tid >> 1)] = exclK;  // bin 2t+1
    }
    if (tid < T_CONST) {
        cursB[i * T_CONST + tid]  = exclB;
        b1endA[i * T_CONST + tid] = inclB;
    }
}

// ---------------------------------------------------------------------------
// scatter: one thread per (i,s); counting-sort via global atomic cursors.
// perm: sorted by key (t, lab1-first). permB: lab1 only, sorted by t.
// tlP: metadata replicated into permuted slot order (kills pair2's
// perm->tlA dependent-load chain).
// ---------------------------------------------------------------------------
__global__ __launch_bounds__(256) void scatter_kernel(
    const int* __restrict__ tlA, int* __restrict__ cursK, int* __restrict__ cursB,
    int* __restrict__ perm, int* __restrict__ permB, int* __restrict__ tlP, int S)
{
    const int gid = blockIdx.x * 256 + threadIdx.x;
    const int i = gid / S;
    const int s = gid - i * S;
    const int tl = tlA[i * S + s];
    const int t = tl & 0xffff, lab = tl >> 16;
    const int slot = atomicAdd(&cursK[i * 2 * T_CONST + t * 2 + (1 - lab)], 1);
    perm[i * S + slot] = s;
    tlP[i * S + slot]  = tl;
    if (lab) {
        const int sb = atomicAdd(&cursB[i * T_CONST + t], 1);
        permB[i * S + sb] = s;
    }
}

// ---------------------------------------------------------------------------
// permute+exp: expF[i][tau][j] = exp(10*cumT[i][tau][perm[j]]);
//              expB[i][tau][jb] = exp(-10*cumT[i][tau][permB[jb]]), jb < n1.
// cum in (0,1] so expF in (1, e^10], expB in [e^-10, 1) — no overflow.
// Gathers stay within one 32KB column (L1-resident); writes coalesced.
// ---------------------------------------------------------------------------
__global__ __launch_bounds__(256) void permute_kernel(
    const float* __restrict__ cumT, const int* __restrict__ perm,
    const int* __restrict__ permB, const int* __restrict__ b1endA,
    float* __restrict__ expF, float* __restrict__ expB, int S)
{
    const int colIdx = blockIdx.x;            // i*T + tau
    const int i = colIdx / T_CONST;
    const float* __restrict__ col = cumT + (size_t)colIdx * S;
    const int n1 = b1endA[i * T_CONST + T_CONST - 1];
    const int chunk = (2 * S) / 8;
    const int beg = blockIdx.y * chunk;
    const int end = beg + chunk;
    for (int idx = beg + (int)threadIdx.x; idx < end; idx += 256) {
        if (idx < S) {
            expF[(size_t)colIdx * S + idx] = __expf(C10 * col[perm[i * S + idx]]);
        } else {
            const int jb = idx - S;
            if (jb < n1)
                expB[(size_t)colIdx * S + jb] = __expf(-C10 * col[permB[i * S + jb]]);
        }
    }
}

// ---------------------------------------------------------------------------
// pair2: one block per (i,j) in perm order (consecutive blocks share columns
// -> L2 locality). Monotone exp => hot loop is pure load/cmp/select/add:
//   fwd: sum of e_s=exp(10 v_s) over suffix [fstart(tk),S) with e_s > e_k,
//        scaled by 1/e_k.
//   bwd: sum of eb_s=exp(-10 v_s) over prefix [0,b1end(cb)) with eb_s > 1/e_k,
//        scaled by e_k.
// Self-exclusion automatic (strict compare / range).
// ---------------------------------------------------------------------------
__global__ __launch_bounds__(256) void pair2_kernel(
    const float* __restrict__ expF, const float* __restrict__ expB,
    const int* __restrict__ tlP, const int* __restrict__ fstartA,
    const int* __restrict__ b1endA, float* __restrict__ partials, int S)
{
    const int bx = blockIdx.x;
    const int i = bx / S;
    const int j = bx - i * S;
    const int tid = threadIdx.x;
    const int tl = tlP[i * S + j];
    const int tk = tl & 0xffff;
    const int lk = tl >> 16;

    float total = 0.f;

    if (lk) {  // forward term at column tk
        const size_t cbase = ((size_t)i * T_CONST + tk) * S;
        const float* __restrict__ cp = expF + cbase;
        const float thr = cp[j];                       // e_k = exp(10 v_k)
        const int lo  = fstartA[i * T_CONST + tk];
        const int loa = (lo + 3) & ~3;
        float sum = 0.f;
        if (tid < loa - lo) { const float e = cp[lo + tid]; sum += (e > thr) ? e : 0.f; }
        for (int p = loa + tid * 4; p < S; p += 1024) {
            const float4 v = *reinterpret_cast<const float4*>(cp + p);
            sum += (v.x > thr) ? v.x : 0.f;
            sum += (v.y > thr) ? v.y : 0.f;
            sum += (v.z > thr) ? v.z : 0.f;
            sum += (v.w > thr) ? v.w : 0.f;
        }
        total += sum * (1.0f / thr);
    }

    if (tk > 0) {  // backward term at column cb
        const int cb = lk ? tk - 1 : tk;
        const size_t cbase = ((size_t)i * T_CONST + cb) * S;
        const float efk = expF[cbase + j];             // exp(10 v_k) at col cb
        const float thr = 1.0f / efk;                  // exp(-10 v_k)
        const float* __restrict__ cp = expB + cbase;
        const int hi  = b1endA[i * T_CONST + cb];
        const int hia = hi & ~3;
        float sum = 0.f;
        for (int p = tid * 4; p < hia; p += 1024) {
            const float4 v = *reinterpret_cast<const float4*>(cp + p);
            sum += (v.x > thr) ? v.x : 0.f;
            sum += (v.y > thr) ? v.y : 0.f;
            sum += (v.z > thr) ? v.z : 0.f;
            sum += (v.w > thr) ? v.w : 0.f;
        }
        if (tid < hi - hia) { const float e = cp[hia + tid]; sum += (e > thr) ? e : 0.f; }
        total += sum * efk;
    }

    for (int off = 32; off > 0; off >>= 1) total += __shfl_down(total, off, 64);
    __shared__ float wsum[4];
    const int lane = tid & 63, wid = tid >> 6;
    if (lane == 0) wsum[wid] = total;
    __syncthreads();
    if (tid == 0) partials[bx] = wsum[0] + wsum[1] + wsum[2] + wsum[3];
}

// ---------------------------------------------------------------------------
// fallback (R1-proven structure): used only if ws_size is too small.
// ---------------------------------------------------------------------------
__global__ __launch_bounds__(256) void pair_kernel(
    const float* __restrict__ cumT, const int* __restrict__ tlA,
    float* __restrict__ partials, int S)
{
    const int bx = blockIdx.x;
    const int i = bx / S;
    const int k = bx - i * S;
    const int base = i * S;
    const int tlk = tlA[base + k];
    const int t_k = tlk & 0xffff;
    const int lab_k = tlk >> 16;
    const bool doF = (lab_k == 1);
    const bool doB = (t_k > 0);
    float sum = 0.f;
    if (doF || doB) {
        const int cb = lab_k ? (t_k > 0 ? t_k - 1 : 0) : t_k;
        const float* __restrict__ colF = cumT + ((size_t)i * T_CONST + t_k) * S;
        const float* __restrict__ colB = cumT + ((size_t)i * T_CONST + cb)  * S;
        const float vf_k = colF[k];
        const float vb_k = colB[k];
        const int* __restrict__ tlp = tlA + base;
        for (int s = threadIdx.x; s < S; s += 256) {
            const int tls = tlp[s];
            const int t_s = tls & 0xffff;
            const int lab_s = tls >> 16;
            if (doF) {
                const float vs = colF[s];
                const bool c = (t_s > t_k) | ((t_s == t_k) & (lab_s == 0));
                if (c & (vs > vf_k)) sum += __expf((vs - vf_k) * C10);
            }
            if (doB) {
                const float vs = colB[s];
                const bool c = (t_s <= cb) & (lab_s == 1);
                if (c & (vb_k > vs)) sum += __expf((vb_k - vs) * C10);
            }
        }
    }
    for (int off = 32; off > 0; off >>= 1) sum += __shfl_down(sum, off, 64);
    __shared__ float wsum[4];
    const int lane = threadIdx.x & 63, wid = threadIdx.x >> 6;
    if (lane == 0) wsum[wid] = sum;
    __syncthreads();
    if (threadIdx.x == 0) partials[bx] = wsum[0] + wsum[1] + wsum[2] + wsum[3];
}

__global__ __launch_bounds__(1024) void reduce_kernel(
    const float* __restrict__ partials, int n, float* __restrict__ out)
{
    float sum = 0.f;
    for (int idx = threadIdx.x; idx < n; idx += 1024) sum += partials[idx];
    for (int off = 32; off > 0; off >>= 1) sum += __shfl_down(sum, off, 64);
    __shared__ float wsum[16];
    const int lane = threadIdx.x & 63, wid = threadIdx.x >> 6;
    if (lane == 0) wsum[wid] = sum;
    __syncthreads();
    if (threadIdx.x == 0) {
        float t = 0.f;
        for (int w = 0; w < 16; ++w) t += wsum[w];
        out[0] = ALPHA_C * t;
    }
}

extern "C" void kernel_launch(void* const* d_in, const int* in_sizes, int n_in,
                              void* d_out, int out_size, void* d_ws, size_t ws_size,
                              hipStream_t stream)
{
    const float* event_out = (const float*)d_in[0];  // (E,S,T) fp32
    const int*   et        = (const int*)d_in[1];    // (S,E) int32
    const int*   labsp     = (const int*)d_in[2];    // (S,E) int32
    const int S = in_sizes[1] / E_CONST;             // 8192

    const size_t colElems = (size_t)E_CONST * T_CONST * S;
    const size_t esElems  = (size_t)E_CONST * S;

    char* p = (char*)d_ws;
    float* cumT     = (float*)p; p += colElems * 4;
    float* expF     = (float*)p; p += colElems * 4;
    float* expB     = (float*)p; p += colElems * 4;
    int*   tlA      = (int*)p;   p += esElems * 4;
    int*   perm     = (int*)p;   p += esElems * 4;
    int*   permB    = (int*)p;   p += esElems * 4;
    int*   tlP      = (int*)p;   p += esElems * 4;
    float* partials = (float*)p; p += esElems * 4;
    int*   fstartA  = (int*)p;   p += E_CONST * T_CONST * 4;
    int*   b1endA   = (int*)p;   p += E_CONST * T_CONST * 4;
    int*   histK    = (int*)p;   p += E_CONST * 2 * T_CONST * 4;
    int*   histB    = (int*)p;   p += E_CONST * T_CONST * 4;
    int*   cursK    = (int*)p;   p += E_CONST * 2 * T_CONST * 4;
    int*   cursB    = (int*)p;   p += E_CONST * T_CONST * 4;
    const size_t needed = (size_t)(p - (char*)d_ws);
    const size_t fallback_needed = colElems * 4 + esElems * 4 * 2;

    const int nB = E_CONST * S;

    if (ws_size >= needed) {
        // zero histograms (tiny, graph-capturable)
        hipMemsetAsync(histK, 0, (size_t)E_CONST * 3 * T_CONST * 4, stream);

        hipLaunchKernelGGL(prep_kernel, dim3(E_CONST * S / 64), dim3(64), 0, stream,
                           event_out, et, labsp, cumT, tlA, histK, histB, S);
        hipLaunchKernelGGL(scan_kernel, dim3(E_CONST), dim3(256), 0, stream,
                           histK, histB, cursK, cursB, fstartA, b1endA);
        hipLaunchKernelGGL(scatter_kernel, dim3(E_CONST * S / 256), dim3(256), 0, stream,
                           tlA, cursK, cursB, perm, permB, tlP, S);
        hipLaunchKernelGGL(permute_kernel, dim3(E_CONST * T_CONST, 8), dim3(256), 0, stream,
                           cumT, perm, permB, b1endA, expF, expB, S);
        hipLaunchKernelGGL(pair2_kernel, dim3(nB), dim3(256), 0, stream,
                           expF, expB, tlP, fstartA, b1endA, partials, S);
        hipLaunchKernelGGL(reduce_kernel, dim3(1), dim3(1024), 0, stream,
                           partials, nB, (float*)d_out);
    } else if (ws_size >= fallback_needed) {
        float* cumT2     = (float*)d_ws;
        int*   tlA2      = (int*)(cumT2 + colElems);
        float* partials2 = (float*)(tlA2 + esElems);
        hipLaunchKernelGGL(prep_kernel, dim3(E_CONST * S / 64), dim3(64), 0, stream,
                           event_out, et, labsp, cumT2, tlA2,
                           (int*)partials2, (int*)partials2, S);
        hipLaunchKernelGGL(pair_kernel, dim3(nB), dim3(256), 0, stream,
                           cumT2, tlA2, partials2, S);
        hipLaunchKernelGGL(reduce_kernel, dim3(1), dim3(1024), 0, stream,
                           partials2, nB, (float*)d_out);
    }
}